// Round 16
// baseline (9913.205 us; speedup 1.0000x reference)
//
#include <hip/hip_runtime.h>
#include <stdint.h>

#define BSZ  128
#define TLEN 8192
#define MDIM 64
#define SDIM 512
#define NEG_BIG (-1e30f)
#define QA   127   // signed-i8-safe quantization range (bytes in [0,127])

typedef int i32x4 __attribute__((ext_vector_type(4)));

// Wave-wide (64-lane) max via DPP, no LDS. Verified R3-R15.
__device__ __forceinline__ float wave_max_f32(float x) {
  int v = __builtin_bit_cast(int, x);
#define DPP_STEP(ctrl)                                                        \
  {                                                                           \
    int o = __builtin_amdgcn_update_dpp(v, v, ctrl, 0xf, 0xf, false);         \
    v = __builtin_bit_cast(int, fmaxf(__builtin_bit_cast(float, v),           \
                                      __builtin_bit_cast(float, o)));         \
  }
  DPP_STEP(0x111)  // row_shr:1
  DPP_STEP(0x112)  // row_shr:2
  DPP_STEP(0x114)  // row_shr:4
  DPP_STEP(0x118)  // row_shr:8
  DPP_STEP(0x142)  // row_bcast15
  DPP_STEP(0x143)  // row_bcast31 -> lane63 has max(0..63)
#undef DPP_STEP
  return __builtin_bit_cast(float, __builtin_amdgcn_readlane(v, 63));
}

// Extract symbol index from one-hot rows: sym[b,t] = argmax_m x[b,t,m]
__global__ void sym_kernel(const float* __restrict__ x, uint8_t* __restrict__ sym) {
  int i = blockIdx.x * blockDim.x + threadIdx.x;  // flat (b,t)
  const float4* p = (const float4*)(x + (size_t)i * MDIM);
  int idx = 0;
  #pragma unroll
  for (int j = 0; j < 16; ++j) {
    float4 v = p[j];
    if (v.x > 0.5f) idx = 4*j + 0;
    if (v.y > 0.5f) idx = 4*j + 1;
    if (v.z > 0.5f) idx = 4*j + 2;
    if (v.w > 0.5f) idx = 4*j + 3;
  }
  sym[i] = (uint8_t)idx;
}

// Per-column max of A (quantization scale). One 64-thread block per column.
__global__ void colmax_kernel(const float* __restrict__ A, float* __restrict__ cmax) {
  int c = blockIdx.x, l = threadIdx.x;
  float m = 0.f;
  for (int r = l; r < SDIM; r += 64) m = fmaxf(m, A[(size_t)r * SDIM + c]);
  #pragma unroll
  for (int off = 32; off; off >>= 1) m = fmaxf(m, __shfl_xor(m, off));
  if (l == 0) cmax[c] = m;
}

// Pack A column-major as u8 row-quads: Aq[c*128 + j] = A[4j..4j+3][c] scaled
__global__ void pack_kernel(const float* __restrict__ A, const float* __restrict__ cmax,
                            unsigned* __restrict__ Aq) {
  int id = blockIdx.x * 256 + threadIdx.x;   // 512*128 = 65536 ids
  int c = id >> 7, j = id & 127;
  float s = (float)QA / cmax[c];
  unsigned q = 0;
  #pragma unroll
  for (int bb = 0; bb < 4; ++bb) {
    float v = A[(size_t)(4 * j + bb) * SDIM + c];
    int qi = (int)(v * s + 0.5f);
    if (qi > QA) qi = QA;
    q |= (unsigned)qi << (8 * bb);
  }
  Aq[c * 128 + j] = q;
}

// Linear-space scaled forward, ONE barrier/step. Per-wave own-scale quant
// pre-barrier; post-barrier the p-bytes are brought to the common scale by
// an UNCONDITIONAL register-uniform rounded byte-shift whose constants are
// SALU (s_cselect, no branches), interleaved tile-by-tile with the MFMAs so
// the rescale VALU co-issues under the matrix pipe (R15's regression was
// 8 scalar branches + rescale on the critical path).
__global__
#if __has_attribute(amdgpu_waves_per_eu)
__attribute__((amdgpu_waves_per_eu(2, 2)))
#endif
__launch_bounds__(512) void hmm_fwd(
    const unsigned* __restrict__ Aq, const float* __restrict__ cmax,
    const float* __restrict__ Bm, const uint8_t* __restrict__ sym,
    float* __restrict__ out) {
  const int b  = blockIdx.x;
  const int t  = threadIdx.x;        // == state owned
  const int wv = t >> 6;             // wave 0..7 -> cols 64wv..64wv+63
  const int ln = t & 63;
  const int pg = ln >> 4;            // K-subgroup / col-tile id

  __shared__ __align__(16) uint8_t p8[2][SDIM];  // quantized p, dbuf
  __shared__ __align__(8)  uint8_t e8[2][8];     // per-wave exponent bytes
  __shared__ float red2[8];

  // ---- B-operand tiles: 4 col-tiles x 8 K-tiles, 32 uint4 (AGPR-parked) ----
  const uint4* aq4 = (const uint4*)Aq;
  const int cb = (wv << 6) + (ln & 15);          // this lane's base col
#define LDB(TT, KT) aq4[(size_t)(cb + 16 * TT) * 32 + KT * 4 + pg]
  uint4 B00=LDB(0,0),B01=LDB(0,1),B02=LDB(0,2),B03=LDB(0,3),
        B04=LDB(0,4),B05=LDB(0,5),B06=LDB(0,6),B07=LDB(0,7);
  uint4 B10=LDB(1,0),B11=LDB(1,1),B12=LDB(1,2),B13=LDB(1,3),
        B14=LDB(1,4),B15=LDB(1,5),B16=LDB(1,6),B17=LDB(1,7);
  uint4 B20=LDB(2,0),B21=LDB(2,1),B22=LDB(2,2),B23=LDB(2,3),
        B24=LDB(2,4),B25=LDB(2,5),B26=LDB(2,6),B27=LDB(2,7);
  uint4 B30=LDB(3,0),B31=LDB(3,1),B32=LDB(3,2),B33=LDB(3,3),
        B34=LDB(3,4),B35=LDB(3,5),B36=LDB(3,6),B37=LDB(3,7);
#undef LDB

  const float cscale = cmax[t] * (1.0f / ((float)QA * (float)QA));
  const uint8_t* symb = sym + (size_t)b * TLEN;

  // ---- init: v0 = exp(alpha0) = (B[s0,0]+eps) for t==0, else 0 ----
  int s0 = symb[0];
  float vReg = (t == 0) ? (Bm[s0 * SDIM + t] + 1e-16f) : 0.f;
  int   E_acc = 0;
  int   symNext = symb[1];
  float Ecur = Bm[symNext * SDIM + t] + 1e-16f;   // E_1 + eps
  symNext = symb[2];

  for (int step = 1; step < TLEN; ++step) {
    const int par = step & 1;

    // ---- pre-barrier: quantize with OWN wave scale ----
    float m_w = wave_max_f32(vReg);
    unsigned ebw = (__builtin_bit_cast(unsigned, m_w) >> 23) & 255u;
    float sqQ = __builtin_bit_cast(float, (253u - ebw) << 23) * (float)QA;
    p8[par][t] = (uint8_t)(unsigned)fmaf(vReg, sqQ, 0.5f);
    if (ln == 0) e8[par][wv] = (uint8_t)ebw;
    __syncthreads();                  // THE barrier (p8 + e8 ready)

    // ---- P loads first (pipelined LDS latency) ----
    const uint4* pq = (const uint4*)p8[par];
    uint4 P0 = pq[0*4+pg], P1 = pq[1*4+pg], P2 = pq[2*4+pg], P3 = pq[3*4+pg];
    uint4 P4 = pq[4*4+pg], P5 = pq[5*4+pg], P6 = pq[6*4+pg], P7 = pq[7*4+pg];
    uint2 ev = *(const uint2*)&e8[par][0];

    // prefetches (hide under MFMA phase)
    float Enxt  = Bm[symNext * SDIM + t] + 1e-16f;
    int   symNN = (int)symb[(step + 2 <= TLEN - 1) ? step + 2 : TLEN - 1];

    // ---- exponents -> scalar domain; all shift constants are SALU ----
    unsigned sx = (unsigned)__builtin_amdgcn_readfirstlane((int)ev.x);
    unsigned sy = (unsigned)__builtin_amdgcn_readfirstlane((int)ev.y);
    unsigned ek0 = sx & 255u, ek1 = (sx >> 8) & 255u,
             ek2 = (sx >> 16) & 255u, ek3 = sx >> 24;
    unsigned ek4 = sy & 255u, ek5 = (sy >> 8) & 255u,
             ek6 = (sy >> 16) & 255u, ek7 = sy >> 24;
    unsigned Ea = ek0 > ek1 ? ek0 : ek1, Eb = ek2 > ek3 ? ek2 : ek3;
    unsigned Ec = ek4 > ek5 ? ek4 : ek5, Ed = ek6 > ek7 ? ek6 : ek7;
    unsigned Ee = Ea > Eb ? Ea : Eb,     Ef = Ec > Ed ? Ec : Ed;
    unsigned E  = Ee > Ef ? Ee : Ef;

    i32x4 l0={0,0,0,0}, l1={0,0,0,0}, l2={0,0,0,0}, l3={0,0,0,0};
    i32x4 h0={0,0,0,0}, h1={0,0,0,0}, h2={0,0,0,0}, h3={0,0,0,0};
#define MF(P, B, C) C = __builtin_amdgcn_mfma_i32_16x16x64_i8(                \
        __builtin_bit_cast(i32x4, P), __builtin_bit_cast(i32x4, B), C, 0, 0, 0)
    // Unconditional rounded byte-shift to common scale E, then 4 MFMA.
    // dm<=15 keeps shifts defined; mk=0 zeroes waves >=8 bits down.
    // Carry-safe: bytes<=127 (QA), rb-byte<=64 for dm<=7.
#define KT_BLOCK(PK, EK, C0, C1, C2, C3, BT0, BT1, BT2, BT3)                  \
    {                                                                         \
      unsigned d  = E - (EK);                                                 \
      unsigned dm = d < 15u ? d : 15u;                                        \
      unsigned rb = (dm && dm < 8u) ? 0x01010101u * (1u << (dm - 1)) : 0u;    \
      unsigned mk = (dm < 8u) ? (0xFFu >> dm) * 0x01010101u : 0u;             \
      PK.x = ((PK.x + rb) >> dm) & mk; PK.y = ((PK.y + rb) >> dm) & mk;       \
      PK.z = ((PK.z + rb) >> dm) & mk; PK.w = ((PK.w + rb) >> dm) & mk;       \
      MF(PK, BT0, C0); MF(PK, BT1, C1); MF(PK, BT2, C2); MF(PK, BT3, C3);     \
    }
    KT_BLOCK(P0, ek0, l0, l1, l2, l3, B00, B10, B20, B30)
    KT_BLOCK(P1, ek1, l0, l1, l2, l3, B01, B11, B21, B31)
    KT_BLOCK(P2, ek2, l0, l1, l2, l3, B02, B12, B22, B32)
    KT_BLOCK(P3, ek3, l0, l1, l2, l3, B03, B13, B23, B33)
    KT_BLOCK(P4, ek4, h0, h1, h2, h3, B04, B14, B24, B34)
    KT_BLOCK(P5, ek5, h0, h1, h2, h3, B05, B15, B25, B35)
    KT_BLOCK(P6, ek6, h0, h1, h2, h3, B06, B16, B26, B36)
    KT_BLOCK(P7, ek7, h0, h1, h2, h3, B07, B17, B27, B37)
#undef KT_BLOCK
#undef MF

    // ---- extract own-column result: tile pg, any row (all rows equal) ----
    int rlo = (pg & 2) ? ((pg & 1) ? l3.x : l2.x)
                       : ((pg & 1) ? l1.x : l0.x);
    int rhi = (pg & 2) ? ((pg & 1) ? h3.x : h2.x)
                       : ((pg & 1) ? h1.x : h0.x);
    int rv = rlo + rhi;

    // ---- v-update (exact ref math in linear space, E_acc ledger) ----
    vReg  = fmaf((float)rv, cscale, 1e-16f) * Ecur;
    E_acc += (int)E - 126;            // common scale was 2^(E-126)
    Ecur  = Enxt;
    symNext = symNN;
  }

  // ---- outputs: alpha_T = log(v) + E_acc*ln2, then loglik ----
  float alphaReg = __logf(vReg) + (float)E_acc * 0.6931471805599453f;
  out[(size_t)b * SDIM + t] = alphaReg;

  float mx = wave_max_f32(alphaReg);
  if (ln == 0) red2[wv] = mx;
  __syncthreads();
  float mf = fmaxf(fmaxf(fmaxf(red2[0], red2[1]), fmaxf(red2[2], red2[3])),
                   fmaxf(fmaxf(red2[4], red2[5]), fmaxf(red2[6], red2[7])));

  float se = __expf(alphaReg - mf);
  #pragma unroll
  for (int off = 32; off; off >>= 1) se += __shfl_xor(se, off);
  __syncthreads();                    // red2 reads done before rewrite
  if (ln == 0) red2[wv] = se;
  __syncthreads();
  if (t == 0) {
    float tot = 0.f;
    #pragma unroll
    for (int k = 0; k < 8; ++k) tot += red2[k];
    out[(size_t)BSZ * SDIM + b] = __logf(tot + SDIM * 1e-16f) + mf;
  }
}

extern "C" void kernel_launch(void* const* d_in, const int* in_sizes, int n_in,
                              void* d_out, int out_size, void* d_ws, size_t ws_size,
                              hipStream_t stream) {
  const float* x  = (const float*)d_in[0];
  const float* A  = (const float*)d_in[1];
  const float* Bm = (const float*)d_in[2];
  float* out = (float*)d_out;

  uint8_t*  sym  = (uint8_t*)d_ws;                                  // 1 MB
  unsigned* Aq   = (unsigned*)((char*)d_ws + (1 << 20));            // 256 KB
  float*    cmax = (float*)((char*)d_ws + (1 << 20) + (256 << 10)); // 2 KB

  sym_kernel<<<(BSZ * TLEN) / 256, 256, 0, stream>>>(x, sym);
  colmax_kernel<<<SDIM, 64, 0, stream>>>(A, cmax);
  pack_kernel<<<(SDIM * 128) / 256, 256, 0, stream>>>(A, cmax, Aq);
  hmm_fwd<<<BSZ, 512, 0, stream>>>(Aq, cmax, Bm, sym, out);
}

// Round 17
// 7599.934 us; speedup vs baseline: 1.3044x; 1.3044x over previous
//
#include <hip/hip_runtime.h>
#include <stdint.h>

#define BSZ  128
#define TLEN 8192
#define MDIM 64
#define SDIM 512
#define NEG_BIG (-1e30f)
#define QA   127   // signed-i8-safe quantization range (bytes in [0,127])

typedef int i32x4 __attribute__((ext_vector_type(4)));

// Wave-wide (64-lane) max via DPP, no LDS. Verified R3-R16.
__device__ __forceinline__ float wave_max_f32(float x) {
  int v = __builtin_bit_cast(int, x);
#define DPP_STEP(ctrl)                                                        \
  {                                                                           \
    int o = __builtin_amdgcn_update_dpp(v, v, ctrl, 0xf, 0xf, false);         \
    v = __builtin_bit_cast(int, fmaxf(__builtin_bit_cast(float, v),           \
                                      __builtin_bit_cast(float, o)));         \
  }
  DPP_STEP(0x111)  // row_shr:1
  DPP_STEP(0x112)  // row_shr:2
  DPP_STEP(0x114)  // row_shr:4
  DPP_STEP(0x118)  // row_shr:8
  DPP_STEP(0x142)  // row_bcast15
  DPP_STEP(0x143)  // row_bcast31 -> lane63 has max(0..63)
#undef DPP_STEP
  return __builtin_bit_cast(float, __builtin_amdgcn_readlane(v, 63));
}

// Extract symbol index from one-hot rows: sym[b,t] = argmax_m x[b,t,m]
__global__ void sym_kernel(const float* __restrict__ x, uint8_t* __restrict__ sym) {
  int i = blockIdx.x * blockDim.x + threadIdx.x;  // flat (b,t)
  const float4* p = (const float4*)(x + (size_t)i * MDIM);
  int idx = 0;
  #pragma unroll
  for (int j = 0; j < 16; ++j) {
    float4 v = p[j];
    if (v.x > 0.5f) idx = 4*j + 0;
    if (v.y > 0.5f) idx = 4*j + 1;
    if (v.z > 0.5f) idx = 4*j + 2;
    if (v.w > 0.5f) idx = 4*j + 3;
  }
  sym[i] = (uint8_t)idx;
}

// Per-column max of A (quantization scale). One 64-thread block per column.
__global__ void colmax_kernel(const float* __restrict__ A, float* __restrict__ cmax) {
  int c = blockIdx.x, l = threadIdx.x;
  float m = 0.f;
  for (int r = l; r < SDIM; r += 64) m = fmaxf(m, A[(size_t)r * SDIM + c]);
  #pragma unroll
  for (int off = 32; off; off >>= 1) m = fmaxf(m, __shfl_xor(m, off));
  if (l == 0) cmax[c] = m;
}

// Pack A column-major as u8 row-quads: Aq[c*128 + j] = A[4j..4j+3][c] scaled
__global__ void pack_kernel(const float* __restrict__ A, const float* __restrict__ cmax,
                            unsigned* __restrict__ Aq) {
  int id = blockIdx.x * 256 + threadIdx.x;   // 512*128 = 65536 ids
  int c = id >> 7, j = id & 127;
  float s = (float)QA / cmax[c];
  unsigned q = 0;
  #pragma unroll
  for (int bb = 0; bb < 4; ++bb) {
    float v = A[(size_t)(4 * j + bb) * SDIM + c];
    int qi = (int)(v * s + 0.5f);
    if (qi > QA) qi = QA;
    q |= (unsigned)qi << (8 * bb);
  }
  Aq[c * 128 + j] = q;
}

// Linear-space scaled forward (R12/R13 math, absmax 0) + EXACT zero-tile
// skip: with global-max quantization, a source wave whose max is >=2^8
// below the global max quantizes to ALL-ZERO bytes -> its K-tile's 4 MFMAs
// contribute exactly 0 and are skipped via a block-uniform scalar branch
// (identity transformation; HMM alphas spread over thousands of nats, so
// typically only 1-2 of 8 tiles are live). Per-wave maxes travel as
// exponent BYTES (one b64 LDS read; E + skip mask in SALU).
__global__
#if __has_attribute(amdgpu_waves_per_eu)
__attribute__((amdgpu_waves_per_eu(2, 2)))
#endif
__launch_bounds__(512) void hmm_fwd(
    const unsigned* __restrict__ Aq, const float* __restrict__ cmax,
    const float* __restrict__ Bm, const uint8_t* __restrict__ sym,
    float* __restrict__ out) {
  const int b  = blockIdx.x;
  const int t  = threadIdx.x;        // == state owned
  const int wv = t >> 6;             // wave 0..7 -> cols 64wv..64wv+63
  const int ln = t & 63;
  const int pg = ln >> 4;            // K-subgroup / col-tile id

  __shared__ __align__(16) uint8_t p8[SDIM];   // quantized p
  __shared__ __align__(8)  uint8_t eb8[8];     // per-wave max-exponent bytes
  __shared__ float red2[8];

  // ---- B-operand tiles: 4 col-tiles x 8 K-tiles, 32 uint4 (AGPR-parked) ----
  const uint4* aq4 = (const uint4*)Aq;
  const int cb = (wv << 6) + (ln & 15);        // this lane's base col
#define LDB(TT, KT) aq4[(size_t)(cb + 16 * TT) * 32 + KT * 4 + pg]
  uint4 B00=LDB(0,0),B01=LDB(0,1),B02=LDB(0,2),B03=LDB(0,3),
        B04=LDB(0,4),B05=LDB(0,5),B06=LDB(0,6),B07=LDB(0,7);
  uint4 B10=LDB(1,0),B11=LDB(1,1),B12=LDB(1,2),B13=LDB(1,3),
        B14=LDB(1,4),B15=LDB(1,5),B16=LDB(1,6),B17=LDB(1,7);
  uint4 B20=LDB(2,0),B21=LDB(2,1),B22=LDB(2,2),B23=LDB(2,3),
        B24=LDB(2,4),B25=LDB(2,5),B26=LDB(2,6),B27=LDB(2,7);
  uint4 B30=LDB(3,0),B31=LDB(3,1),B32=LDB(3,2),B33=LDB(3,3),
        B34=LDB(3,4),B35=LDB(3,5),B36=LDB(3,6),B37=LDB(3,7);
#undef LDB

  const float cscale = cmax[t] * (1.0f / ((float)QA * (float)QA));
  const uint8_t* symb = sym + (size_t)b * TLEN;

  // ---- init: v0 = exp(alpha0) = (B[s0,0]+eps) for t==0, else 0 ----
  int s0 = symb[0];
  float vReg = (t == 0) ? (Bm[s0 * SDIM + t] + 1e-16f) : 0.f;
  int   E_acc = 0;
  int   symNext = symb[1];
  float Ecur = Bm[symNext * SDIM + t] + 1e-16f;   // E_1 + eps
  symNext = symb[2];

  for (int step = 1; step < TLEN; ++step) {
    // ---- phase A: per-wave max exponent byte -> eb8; E prefetch ----
    float m_w = wave_max_f32(vReg);
    unsigned ebw = (__builtin_bit_cast(unsigned, m_w) >> 23) & 255u;
    if (ln == 0) eb8[wv] = (uint8_t)ebw;
    float Enxt  = Bm[symNext * SDIM + t] + 1e-16f;
    int   symNN = (int)symb[(step + 2 <= TLEN - 1) ? step + 2 : TLEN - 1];
    __syncthreads();                  // B1: eb8 ready

    // ---- phase B: E + skip mask (SALU), quantize, publish p ----
    uint2 ev = *(const uint2*)&eb8[0];                  // one b64 read
    unsigned sx = (unsigned)__builtin_amdgcn_readfirstlane((int)ev.x);
    unsigned sy = (unsigned)__builtin_amdgcn_readfirstlane((int)ev.y);
    unsigned ek0 = sx & 255u, ek1 = (sx >> 8) & 255u,
             ek2 = (sx >> 16) & 255u, ek3 = sx >> 24;
    unsigned ek4 = sy & 255u, ek5 = (sy >> 8) & 255u,
             ek6 = (sy >> 16) & 255u, ek7 = sy >> 24;
    unsigned Ea = ek0 > ek1 ? ek0 : ek1, Eb = ek2 > ek3 ? ek2 : ek3;
    unsigned Ec = ek4 > ek5 ? ek4 : ek5, Ed = ek6 > ek7 ? ek6 : ek7;
    unsigned Ee = Ea > Eb ? Ea : Eb,     Ef = Ec > Ed ? Ec : Ed;
    unsigned E  = Ee > Ef ? Ee : Ef;

    float sqQ = __builtin_bit_cast(float, (253u - E) << 23) * (float)QA;
    p8[t] = (uint8_t)(unsigned)fmaf(vReg, sqQ, 0.5f);
    __syncthreads();                  // B2: p8 ready

    // ---- phase C: P loads (batched), then masked 4-MFMA tile blocks ----
    const uint4* pq = (const uint4*)p8;
    uint4 P0 = pq[0*4+pg], P1 = pq[1*4+pg], P2 = pq[2*4+pg], P3 = pq[3*4+pg];
    uint4 P4 = pq[4*4+pg], P5 = pq[5*4+pg], P6 = pq[6*4+pg], P7 = pq[7*4+pg];

    i32x4 l0={0,0,0,0}, l1={0,0,0,0}, l2={0,0,0,0}, l3={0,0,0,0};
    i32x4 h0={0,0,0,0}, h1={0,0,0,0}, h2={0,0,0,0}, h3={0,0,0,0};
#define MF(P, B, C) C = __builtin_amdgcn_mfma_i32_16x16x64_i8(                \
        __builtin_bit_cast(i32x4, P), __builtin_bit_cast(i32x4, B), C, 0, 0, 0)
    // Exact skip: wave k's bytes are all zero when E - ek >= 8
    // (round(127*2^(ek-E)) == 0) -> its 4 MFMAs are identity-skippable.
    if (E - ek0 < 8u) { MF(P0, B00, l0); MF(P0, B10, l1); MF(P0, B20, l2); MF(P0, B30, l3); }
    if (E - ek1 < 8u) { MF(P1, B01, l0); MF(P1, B11, l1); MF(P1, B21, l2); MF(P1, B31, l3); }
    if (E - ek2 < 8u) { MF(P2, B02, l0); MF(P2, B12, l1); MF(P2, B22, l2); MF(P2, B32, l3); }
    if (E - ek3 < 8u) { MF(P3, B03, l0); MF(P3, B13, l1); MF(P3, B23, l2); MF(P3, B33, l3); }
    if (E - ek4 < 8u) { MF(P4, B04, h0); MF(P4, B14, h1); MF(P4, B24, h2); MF(P4, B34, h3); }
    if (E - ek5 < 8u) { MF(P5, B05, h0); MF(P5, B15, h1); MF(P5, B25, h2); MF(P5, B35, h3); }
    if (E - ek6 < 8u) { MF(P6, B06, h0); MF(P6, B16, h1); MF(P6, B26, h2); MF(P6, B36, h3); }
    if (E - ek7 < 8u) { MF(P7, B07, h0); MF(P7, B17, h1); MF(P7, B27, h2); MF(P7, B37, h3); }
#undef MF

    // ---- extract own-column result: tile pg, any row (all rows equal) ----
    int rlo = (pg & 2) ? ((pg & 1) ? l3.x : l2.x)
                       : ((pg & 1) ? l1.x : l0.x);
    int rhi = (pg & 2) ? ((pg & 1) ? h3.x : h2.x)
                       : ((pg & 1) ? h1.x : h0.x);
    int rv = rlo + rhi;

    // ---- v-update (exact ref math in linear space, E_acc ledger) ----
    vReg  = fmaf((float)rv, cscale, 1e-16f) * Ecur;
    E_acc += (int)E - 126;            // common scale was 2^(E-126)
    Ecur  = Enxt;
    symNext = symNN;
  }

  // ---- outputs: alpha_T = log(v) + E_acc*ln2, then loglik ----
  float alphaReg = __logf(vReg) + (float)E_acc * 0.6931471805599453f;
  out[(size_t)b * SDIM + t] = alphaReg;

  float mx = wave_max_f32(alphaReg);
  if (ln == 0) red2[wv] = mx;
  __syncthreads();
  float mf = fmaxf(fmaxf(fmaxf(red2[0], red2[1]), fmaxf(red2[2], red2[3])),
                   fmaxf(fmaxf(red2[4], red2[5]), fmaxf(red2[6], red2[7])));

  float se = __expf(alphaReg - mf);
  #pragma unroll
  for (int off = 32; off; off >>= 1) se += __shfl_xor(se, off);
  __syncthreads();                    // red2 reads done before rewrite
  if (ln == 0) red2[wv] = se;
  __syncthreads();
  if (t == 0) {
    float tot = 0.f;
    #pragma unroll
    for (int k = 0; k < 8; ++k) tot += red2[k];
    out[(size_t)BSZ * SDIM + b] = __logf(tot + SDIM * 1e-16f) + mf;
  }
}

extern "C" void kernel_launch(void* const* d_in, const int* in_sizes, int n_in,
                              void* d_out, int out_size, void* d_ws, size_t ws_size,
                              hipStream_t stream) {
  const float* x  = (const float*)d_in[0];
  const float* A  = (const float*)d_in[1];
  const float* Bm = (const float*)d_in[2];
  float* out = (float*)d_out;

  uint8_t*  sym  = (uint8_t*)d_ws;                                  // 1 MB
  unsigned* Aq   = (unsigned*)((char*)d_ws + (1 << 20));            // 256 KB
  float*    cmax = (float*)((char*)d_ws + (1 << 20) + (256 << 10)); // 2 KB

  sym_kernel<<<(BSZ * TLEN) / 256, 256, 0, stream>>>(x, sym);
  colmax_kernel<<<SDIM, 64, 0, stream>>>(A, cmax);
  pack_kernel<<<(SDIM * 128) / 256, 256, 0, stream>>>(A, cmax, Aq);
  hmm_fwd<<<BSZ, 512, 0, stream>>>(Aq, cmax, Bm, sym, out);
}

// Round 18
// 6858.583 us; speedup vs baseline: 1.4454x; 1.1081x over previous
//
#include <hip/hip_runtime.h>
#include <stdint.h>

#define BSZ  128
#define TLEN 8192
#define MDIM 64
#define SDIM 512
#define NEG_BIG (-1e30f)
#define QA   127   // signed-i8-safe quantization range (bytes in [0,127])

typedef int i32x4 __attribute__((ext_vector_type(4)));

// Wave-wide (64-lane) max via DPP, no LDS. Verified R3-R17 (absmax 0).
__device__ __forceinline__ float wave_max_f32(float x) {
  int v = __builtin_bit_cast(int, x);
#define DPP_STEP(ctrl)                                                        \
  {                                                                           \
    int o = __builtin_amdgcn_update_dpp(v, v, ctrl, 0xf, 0xf, false);         \
    v = __builtin_bit_cast(int, fmaxf(__builtin_bit_cast(float, v),           \
                                      __builtin_bit_cast(float, o)));         \
  }
  DPP_STEP(0x111)  // row_shr:1
  DPP_STEP(0x112)  // row_shr:2
  DPP_STEP(0x114)  // row_shr:4
  DPP_STEP(0x118)  // row_shr:8
  DPP_STEP(0x142)  // row_bcast15
  DPP_STEP(0x143)  // row_bcast31 -> lane63 has max(0..63)
#undef DPP_STEP
  return __builtin_bit_cast(float, __builtin_amdgcn_readlane(v, 63));
}

// Extract symbol index from one-hot rows: sym[b,t] = argmax_m x[b,t,m]
__global__ void sym_kernel(const float* __restrict__ x, uint8_t* __restrict__ sym) {
  int i = blockIdx.x * blockDim.x + threadIdx.x;  // flat (b,t)
  const float4* p = (const float4*)(x + (size_t)i * MDIM);
  int idx = 0;
  #pragma unroll
  for (int j = 0; j < 16; ++j) {
    float4 v = p[j];
    if (v.x > 0.5f) idx = 4*j + 0;
    if (v.y > 0.5f) idx = 4*j + 1;
    if (v.z > 0.5f) idx = 4*j + 2;
    if (v.w > 0.5f) idx = 4*j + 3;
  }
  sym[i] = (uint8_t)idx;
}

// Per-column max of A (quantization scale). One 64-thread block per column.
__global__ void colmax_kernel(const float* __restrict__ A, float* __restrict__ cmax) {
  int c = blockIdx.x, l = threadIdx.x;
  float m = 0.f;
  for (int r = l; r < SDIM; r += 64) m = fmaxf(m, A[(size_t)r * SDIM + c]);
  #pragma unroll
  for (int off = 32; off; off >>= 1) m = fmaxf(m, __shfl_xor(m, off));
  if (l == 0) cmax[c] = m;
}

// Pack A column-major as u8 row-quads: Aq[c*128 + j] = A[4j..4j+3][c] scaled
// to [0,127] by column max (signed-i8-safe for MFMA).
__global__ void pack_kernel(const float* __restrict__ A, const float* __restrict__ cmax,
                            unsigned* __restrict__ Aq) {
  int id = blockIdx.x * 256 + threadIdx.x;   // 512*128 = 65536 ids
  int c = id >> 7, j = id & 127;
  float s = (float)QA / cmax[c];
  unsigned q = 0;
  #pragma unroll
  for (int bb = 0; bb < 4; ++bb) {
    float v = A[(size_t)(4 * j + bb) * SDIM + c];
    int qi = (int)(v * s + 0.5f);
    if (qi > QA) qi = QA;
    q |= (unsigned)qi << (8 * bb);
  }
  Aq[c * 128 + j] = q;
}

// Linear-space scaled forward (verified absmax 0; best measured 6849 us).
// One block per batch; 512 threads / 8 waves; thread t owns state t.
// Per step: wave-max (DPP) -> B1 -> global max + pow2-exponent quantize
// (no exp) -> B2 -> 8 LDS uint4 reads + 32 mfma_i32_16x16x64_i8 in 8
// independent 4-deep chains -> in-register v-update (no log). Exact
// exponent ledger E_acc; alpha = log(v) + E_acc*ln2 once at the end.
// Structural budget per SIMD-step: ~1024-1300cy MFMA issue (M=1 in a
// 16x16 tile -- irreducible for i8) + ~700-980cy serial (2 barriers,
// 2 LDS round-trips, reduce/quant). R14-R17 falsified all alternatives:
// VALU offload (L2 wall), single-barrier P-rescale (VALU on MFMA path),
// zero-tile skip (no sparsity in the mixed distribution).
__global__
#if __has_attribute(amdgpu_waves_per_eu)
__attribute__((amdgpu_waves_per_eu(2, 2)))
#endif
__launch_bounds__(512) void hmm_fwd(
    const unsigned* __restrict__ Aq, const float* __restrict__ cmax,
    const float* __restrict__ Bm, const uint8_t* __restrict__ sym,
    float* __restrict__ out) {
  const int b  = blockIdx.x;
  const int t  = threadIdx.x;        // == state owned
  const int wv = t >> 6;             // wave 0..7 -> cols 64wv..64wv+63
  const int ln = t & 63;
  const int pg = ln >> 4;            // K-subgroup / col-tile id

  __shared__ __align__(16) uint8_t p8[SDIM];   // quantized p
  __shared__ float red[8];                     // per-wave v maxes
  __shared__ float red2[8];

  // ---- B-operand tiles: 4 col-tiles x 8 K-tiles, 32 named uint4 ----
  const uint4* aq4 = (const uint4*)Aq;
  const int cb = (wv << 6) + (ln & 15);        // this lane's base col
#define LDB(TT, KT) aq4[(size_t)(cb + 16 * TT) * 32 + KT * 4 + pg]
  uint4 B00=LDB(0,0),B01=LDB(0,1),B02=LDB(0,2),B03=LDB(0,3),
        B04=LDB(0,4),B05=LDB(0,5),B06=LDB(0,6),B07=LDB(0,7);
  uint4 B10=LDB(1,0),B11=LDB(1,1),B12=LDB(1,2),B13=LDB(1,3),
        B14=LDB(1,4),B15=LDB(1,5),B16=LDB(1,6),B17=LDB(1,7);
  uint4 B20=LDB(2,0),B21=LDB(2,1),B22=LDB(2,2),B23=LDB(2,3),
        B24=LDB(2,4),B25=LDB(2,5),B26=LDB(2,6),B27=LDB(2,7);
  uint4 B30=LDB(3,0),B31=LDB(3,1),B32=LDB(3,2),B33=LDB(3,3),
        B34=LDB(3,4),B35=LDB(3,5),B36=LDB(3,6),B37=LDB(3,7);
#undef LDB

  const float cscale = cmax[t] * (1.0f / ((float)QA * (float)QA));
  const uint8_t* symb = sym + (size_t)b * TLEN;

  // ---- init: v0 = exp(alpha0) = (B[s0,0]+eps) for t==0, else 0 ----
  int s0 = symb[0];
  float vReg = (t == 0) ? (Bm[s0 * SDIM + t] + 1e-16f) : 0.f;
  int   E_acc = 0;
  int   symNext = symb[1];
  float Ecur = Bm[symNext * SDIM + t] + 1e-16f;   // E_1 + eps
  symNext = symb[2];

  for (int step = 1; step < TLEN; ++step) {
    // ---- phase A: per-wave max -> red; issue next-E prefetch early ----
    float m_w = wave_max_f32(vReg);
    if (ln == 0) red[wv] = m_w;
    float Enxt  = Bm[symNext * SDIM + t] + 1e-16f;           // L2-hot
    int   symNN = (int)symb[(step + 2 <= TLEN - 1) ? step + 2 : TLEN - 1];
    __syncthreads();                  // B1: red ready

    // ---- phase B: global max -> pow2 scale -> quantize (no exp) ----
    float4 ra = *(const float4*)&red[0];
    float4 rb = *(const float4*)&red[4];
    float gm = fmaxf(fmaxf(fmaxf(ra.x, ra.y), fmaxf(ra.z, ra.w)),
                     fmaxf(fmaxf(rb.x, rb.y), fmaxf(rb.z, rb.w)));
    unsigned eb = (__builtin_bit_cast(unsigned, gm) >> 23) & 255u;
    // sqQ = 2^(-e-1) * QA  (e = eb-127); v*sqQ in (0, QA] for v <= gm
    float sqQ = __builtin_bit_cast(float, (253u - eb) << 23) * (float)QA;
    unsigned q = (unsigned)fmaf(vReg, sqQ, 0.5f);
    p8[t] = (uint8_t)q;
    __syncthreads();                  // B2: p8 ready

    // ---- phase C: load ALL 8 P-operands (pipelined), then 32 MFMA in
    //      8 independent 4-deep chains (2 half-K chains per col-tile) ----
    const uint4* pq = (const uint4*)p8;
    uint4 P0 = pq[0*4+pg], P1 = pq[1*4+pg], P2 = pq[2*4+pg], P3 = pq[3*4+pg];
    uint4 P4 = pq[4*4+pg], P5 = pq[5*4+pg], P6 = pq[6*4+pg], P7 = pq[7*4+pg];

    i32x4 l0={0,0,0,0}, l1={0,0,0,0}, l2={0,0,0,0}, l3={0,0,0,0};
    i32x4 h0={0,0,0,0}, h1={0,0,0,0}, h2={0,0,0,0}, h3={0,0,0,0};
#define MF(P, B, C) C = __builtin_amdgcn_mfma_i32_16x16x64_i8(              \
        __builtin_bit_cast(i32x4, P), __builtin_bit_cast(i32x4, B), C, 0, 0, 0)
    MF(P0, B00, l0); MF(P0, B10, l1); MF(P0, B20, l2); MF(P0, B30, l3);
    MF(P4, B04, h0); MF(P4, B14, h1); MF(P4, B24, h2); MF(P4, B34, h3);
    MF(P1, B01, l0); MF(P1, B11, l1); MF(P1, B21, l2); MF(P1, B31, l3);
    MF(P5, B05, h0); MF(P5, B15, h1); MF(P5, B25, h2); MF(P5, B35, h3);
    MF(P2, B02, l0); MF(P2, B12, l1); MF(P2, B22, l2); MF(P2, B32, l3);
    MF(P6, B06, h0); MF(P6, B16, h1); MF(P6, B26, h2); MF(P6, B36, h3);
    MF(P3, B03, l0); MF(P3, B13, l1); MF(P3, B23, l2); MF(P3, B33, l3);
    MF(P7, B07, h0); MF(P7, B17, h1); MF(P7, B27, h2); MF(P7, B37, h3);
#undef MF

    // thread t's own column result: tile pg, any row (all rows equal)
    int rlo = (pg & 2) ? ((pg & 1) ? l3.x : l2.x)
                       : ((pg & 1) ? l1.x : l0.x);
    int rhi = (pg & 2) ? ((pg & 1) ? h3.x : h2.x)
                       : ((pg & 1) ? h1.x : h0.x);
    int rv = rlo + rhi;

    // ---- v-update, fully in-register (exact ref math in linear space) ----
    vReg  = fmaf((float)rv, cscale, 1e-16f) * Ecur;
    E_acc += (int)eb - 126;           // e+1, exact ledger
    Ecur  = Enxt;
    symNext = symNN;
  }

  // ---- outputs: alpha_T = log(v) + E_acc*ln2, then loglik ----
  float alphaReg = __logf(vReg) + (float)E_acc * 0.6931471805599453f;
  out[(size_t)b * SDIM + t] = alphaReg;

  float mx = wave_max_f32(alphaReg);
  if (ln == 0) red2[wv] = mx;
  __syncthreads();
  float mf = fmaxf(fmaxf(fmaxf(red2[0], red2[1]), fmaxf(red2[2], red2[3])),
                   fmaxf(fmaxf(red2[4], red2[5]), fmaxf(red2[6], red2[7])));

  float se = __expf(alphaReg - mf);
  #pragma unroll
  for (int off = 32; off; off >>= 1) se += __shfl_xor(se, off);
  __syncthreads();                    // red2 reads done before rewrite
  if (ln == 0) red2[wv] = se;
  __syncthreads();
  if (t == 0) {
    float tot = 0.f;
    #pragma unroll
    for (int k = 0; k < 8; ++k) tot += red2[k];
    out[(size_t)BSZ * SDIM + b] = __logf(tot + SDIM * 1e-16f) + mf;
  }
}

extern "C" void kernel_launch(void* const* d_in, const int* in_sizes, int n_in,
                              void* d_out, int out_size, void* d_ws, size_t ws_size,
                              hipStream_t stream) {
  const float* x  = (const float*)d_in[0];
  const float* A  = (const float*)d_in[1];
  const float* Bm = (const float*)d_in[2];
  float* out = (float*)d_out;

  uint8_t*  sym  = (uint8_t*)d_ws;                                  // 1 MB
  unsigned* Aq   = (unsigned*)((char*)d_ws + (1 << 20));            // 256 KB
  float*    cmax = (float*)((char*)d_ws + (1 << 20) + (256 << 10)); // 2 KB

  sym_kernel<<<(BSZ * TLEN) / 256, 256, 0, stream>>>(x, sym);
  colmax_kernel<<<SDIM, 64, 0, stream>>>(A, cmax);
  pack_kernel<<<(SDIM * 128) / 256, 256, 0, stream>>>(A, cmax, Aq);
  hmm_fwd<<<BSZ, 512, 0, stream>>>(Aq, cmax, Bm, sym, out);
}